// Round 1
// baseline (2508.250 us; speedup 1.0000x reference)
//
#include <hip/hip_runtime.h>
#include <math.h>

#define N_NODES 131072
#define N_DST   16384
#define DEG     16
#define HID     256

typedef __bf16 bf16_8 __attribute__((ext_vector_type(8)));
typedef float  f32_4  __attribute__((ext_vector_type(4)));

__device__ __forceinline__ float gelu_f(float v) {
    return 0.5f * v * (1.0f + erff(v * 0.70710678f));
}
__device__ __forceinline__ f32_4 zero4() {
    f32_4 z; z[0] = 0.f; z[1] = 0.f; z[2] = 0.f; z[3] = 0.f; return z;
}

// ---------------- prep: fp32 -> bf16 weights ----------------
// layout (elements): w2b[65536] w3b[65536] mw1b[262144] mw2b[131072] mw3b[65536]
__global__ void prep_kernel(__bf16* __restrict__ out,
                            const float* __restrict__ w2,
                            const float* __restrict__ w3,
                            const float* __restrict__ mw1,
                            const float* __restrict__ mw2,
                            const float* __restrict__ mw3) {
    int stride = gridDim.x * blockDim.x;
    for (int i = blockIdx.x * blockDim.x + threadIdx.x; i < 589824; i += stride) {
        float v;
        if      (i <  65536) v = w2[i];
        else if (i < 131072) v = w3[i - 65536];
        else if (i < 393216) v = mw1[i - 131072];
        else if (i < 524288) v = mw2[i - 393216];
        else                 v = mw3[i - 524288];
        out[i] = (__bf16)v;
    }
}

// ---------------- encoder: h = MLP(x) + fourier(pos), bf16 out ----------------
// block = 256 threads = 4 waves, 64 nodes/block; wave w owns rows w*16..w*16+15
__global__ __launch_bounds__(256) void encoder_kernel(
    const float* __restrict__ x, const float* __restrict__ pos,
    const float* __restrict__ w1, const float* __restrict__ b1,
    const __bf16* __restrict__ w2, const float* __restrict__ b2,
    const __bf16* __restrict__ w3, const float* __restrict__ b3,
    const float* __restrict__ bfour,
    __bf16* __restrict__ hout) {
    __shared__ float s_w1[3 * 256];
    __shared__ float s_b1[256];
    __shared__ float s_x[64 * 3];
    __shared__ float s_pos[64 * 2];
    __shared__ __align__(16) __bf16 s_h[64 * 256];  // swizzled: elem (m,k) -> m*256 + ((k + m*8)&255)

    const int tid = threadIdx.x;
    const int node0 = blockIdx.x * 64;

    s_w1[tid]       = w1[tid * 3 + 0];
    s_w1[256 + tid] = w1[tid * 3 + 1];
    s_w1[512 + tid] = w1[tid * 3 + 2];
    s_b1[tid]       = b1[tid];
    if (tid < 192) s_x[tid] = x[node0 * 3 + tid];
    if (tid < 128) s_pos[tid] = pos[node0 * 2 + tid];
    __syncthreads();

    // L1 (K=3): thread = feature j, loop nodes
    {
        const float wa = s_w1[tid], wb = s_w1[256 + tid], wc = s_w1[512 + tid], bb = s_b1[tid];
        #pragma unroll 4
        for (int n = 0; n < 64; n++) {
            float v = fmaf(s_x[n * 3 + 2], wc,
                      fmaf(s_x[n * 3 + 1], wb,
                      fmaf(s_x[n * 3 + 0], wa, bb)));
            s_h[n * 256 + ((tid + n * 8) & 255)] = (__bf16)gelu_f(v);
        }
    }
    __syncthreads();

    const int wave = tid >> 6;
    const int lane = tid & 63;
    const int ln   = lane & 15;
    const int quad = lane >> 4;
    const int mA   = wave * 16 + ln;  // A-row (block-local), A[m=lane&15][k=quad*8+j]

    f32_4 acc[16];

    // L2: MFMA over K=256, N=256
    #pragma unroll
    for (int i = 0; i < 16; i++) acc[i] = zero4();
    #pragma unroll
    for (int ks = 0; ks < 8; ks++) {
        int k0 = ks * 32 + quad * 8;
        bf16_8 a = *(const bf16_8*)&s_h[mA * 256 + ((k0 + mA * 8) & 255)];
        #pragma unroll
        for (int nt = 0; nt < 16; nt++) {
            bf16_8 b = *(const bf16_8*)(w2 + (nt * 16 + ln) * 256 + k0);
            acc[nt] = __builtin_amdgcn_mfma_f32_16x16x32_bf16(a, b, acc[nt], 0, 0, 0);
        }
    }
    __syncthreads();
    // h2 = gelu(acc + b2) -> s_h (C layout: col=lane&15, row=quad*4+reg)
    #pragma unroll
    for (int nt = 0; nt < 16; nt++) {
        int col = nt * 16 + ln;
        float bv = b2[col];
        #pragma unroll
        for (int r = 0; r < 4; r++) {
            int row = wave * 16 + quad * 4 + r;
            s_h[row * 256 + ((col + row * 8) & 255)] = (__bf16)gelu_f(acc[nt][r] + bv);
        }
    }
    __syncthreads();

    // L3: MFMA over K=256, N=256
    #pragma unroll
    for (int i = 0; i < 16; i++) acc[i] = zero4();
    #pragma unroll
    for (int ks = 0; ks < 8; ks++) {
        int k0 = ks * 32 + quad * 8;
        bf16_8 a = *(const bf16_8*)&s_h[mA * 256 + ((k0 + mA * 8) & 255)];
        #pragma unroll
        for (int nt = 0; nt < 16; nt++) {
            bf16_8 b = *(const bf16_8*)(w3 + (nt * 16 + ln) * 256 + k0);
            acc[nt] = __builtin_amdgcn_mfma_f32_16x16x32_bf16(a, b, acc[nt], 0, 0, 0);
        }
    }
    // epilogue: + b3 + [cos|sin](2pi * pos . B_row), store bf16 h
    #pragma unroll
    for (int nt = 0; nt < 16; nt++) {
        int col = nt * 16 + ln;
        float bv = b3[col];
        int jm = col & 127;
        float B0 = bfour[jm * 2 + 0] * 6.2831853071795864f;
        float B1 = bfour[jm * 2 + 1] * 6.2831853071795864f;
        #pragma unroll
        for (int r = 0; r < 4; r++) {
            int row = wave * 16 + quad * 4 + r;
            float f = s_pos[row * 2 + 0] * B0 + s_pos[row * 2 + 1] * B1;
            float ff = (col < 128) ? cosf(f) : sinf(f);
            hout[(node0 + row) * 256 + col] = (__bf16)(acc[nt][r] + bv + ff);
        }
    }
}

// ---------------- messages + segment-mean pool ----------------
// block = 4 waves; wave = 1 dst group (16 edges = one 16-row M-tile)
__global__ __launch_bounds__(256) void message_kernel(
    const __bf16* __restrict__ h, const int* __restrict__ edges,
    const __bf16* __restrict__ w1, const float* __restrict__ b1,
    const __bf16* __restrict__ w2, const float* __restrict__ b2,
    const __bf16* __restrict__ w3, const float* __restrict__ b3,
    float* __restrict__ out) {
    __shared__ __align__(16) __bf16 s_m1[4][16 * 128];  // per-wave layer1 chunk
    __shared__ __align__(16) __bf16 s_m2[4][16 * 256];  // per-wave layer2 out

    const int tid  = threadIdx.x;
    const int wave = tid >> 6;
    const int lane = tid & 63;
    const int ln   = lane & 15;
    const int quad = lane >> 4;
    const int g    = blockIdx.x * 4 + wave;  // dst group id

    const int e   = g * DEG + ln;
    const int src = edges[2 * e + 1];
    const int dst = edges[2 * (g * DEG)];  // uniform across group
    const __bf16* hsrc = h + (size_t)src * HID;
    const __bf16* hdst = h + (size_t)dst * HID;

    f32_4 acc2[16];
    #pragma unroll
    for (int i = 0; i < 16; i++) acc2[i] = zero4();

    // layer1 in N-chunks of 128; each chunk immediately feeds layer2 partial K
    #pragma unroll 1
    for (int c = 0; c < 4; c++) {
        f32_4 acc1[8];
        #pragma unroll
        for (int i = 0; i < 8; i++) acc1[i] = zero4();
        #pragma unroll
        for (int ks = 0; ks < 16; ks++) {
            int k0 = ks * 32 + quad * 8;  // 0..511 over concat(h[src], h[dst])
            bf16_8 a = (ks < 8) ? *(const bf16_8*)(hsrc + k0)
                                : *(const bf16_8*)(hdst + (k0 - 256));
            #pragma unroll
            for (int nt = 0; nt < 8; nt++) {
                int n = c * 128 + nt * 16 + ln;
                bf16_8 b = *(const bf16_8*)(w1 + n * 512 + k0);
                acc1[nt] = __builtin_amdgcn_mfma_f32_16x16x32_bf16(a, b, acc1[nt], 0, 0, 0);
            }
        }
        // m1 chunk: gelu(acc1 + b1) -> LDS (swizzled)
        #pragma unroll
        for (int nt = 0; nt < 8; nt++) {
            int ncol = c * 128 + nt * 16 + ln;
            float bv = b1[ncol];
            int kk = nt * 16 + ln;  // col within chunk
            #pragma unroll
            for (int r = 0; r < 4; r++) {
                int row = quad * 4 + r;
                s_m1[wave][row * 128 + ((kk + row * 8) & 127)] = (__bf16)gelu_f(acc1[nt][r] + bv);
            }
        }
        __syncthreads();
        // layer2 partial accumulation over this K-chunk
        #pragma unroll
        for (int ks2 = 0; ks2 < 4; ks2++) {
            int kk0 = ks2 * 32 + quad * 8;  // 0..127 in chunk
            bf16_8 a2 = *(const bf16_8*)&s_m1[wave][ln * 128 + ((kk0 + ln * 8) & 127)];
            #pragma unroll
            for (int nt2 = 0; nt2 < 16; nt2++) {
                bf16_8 b = *(const bf16_8*)(w2 + (nt2 * 16 + ln) * 512 + c * 128 + kk0);
                acc2[nt2] = __builtin_amdgcn_mfma_f32_16x16x32_bf16(a2, b, acc2[nt2], 0, 0, 0);
            }
        }
        __syncthreads();
    }

    // m2 = gelu(acc2 + b2) -> LDS
    #pragma unroll
    for (int nt = 0; nt < 16; nt++) {
        int ncol = nt * 16 + ln;
        float bv = b2[ncol];
        #pragma unroll
        for (int r = 0; r < 4; r++) {
            int row = quad * 4 + r;
            s_m2[wave][row * 256 + ((ncol + row * 8) & 255)] = (__bf16)gelu_f(acc2[nt][r] + bv);
        }
    }
    __syncthreads();

    // layer3 (reuse acc2 as accumulator)
    #pragma unroll
    for (int i = 0; i < 16; i++) acc2[i] = zero4();
    #pragma unroll
    for (int ks = 0; ks < 8; ks++) {
        int k0 = ks * 32 + quad * 8;
        bf16_8 a = *(const bf16_8*)&s_m2[wave][ln * 256 + ((k0 + ln * 8) & 255)];
        #pragma unroll
        for (int nt = 0; nt < 16; nt++) {
            bf16_8 b = *(const bf16_8*)(w3 + (nt * 16 + ln) * 256 + k0);
            acc2[nt] = __builtin_amdgcn_mfma_f32_16x16x32_bf16(a, b, acc2[nt], 0, 0, 0);
        }
    }
    // pool: mean over the 16 rows of this tile (= the dst group) + b3
    #pragma unroll
    for (int nt = 0; nt < 16; nt++) {
        int ncol = nt * 16 + ln;
        float s = acc2[nt][0] + acc2[nt][1] + acc2[nt][2] + acc2[nt][3];
        s += __shfl_xor(s, 16);
        s += __shfl_xor(s, 32);
        if (quad == 0) out[(size_t)dst * HID + ncol] = s * 0.0625f + b3[ncol];
    }
}

extern "C" void kernel_launch(void* const* d_in, const int* in_sizes, int n_in,
                              void* d_out, int out_size, void* d_ws, size_t ws_size,
                              hipStream_t stream) {
    const float* x     = (const float*)d_in[0];
    const float* pos   = (const float*)d_in[1];
    const int*   edges = (const int*)d_in[2];
    // d_in[3] = batch_idx (unused by reference math)
    const float* ip_w1 = (const float*)d_in[4];
    const float* ip_b1 = (const float*)d_in[5];
    const float* ip_w2 = (const float*)d_in[6];
    const float* ip_b2 = (const float*)d_in[7];
    const float* ip_w3 = (const float*)d_in[8];
    const float* ip_b3 = (const float*)d_in[9];
    const float* bfour = (const float*)d_in[10];
    const float* mw1   = (const float*)d_in[11];
    const float* mb1   = (const float*)d_in[12];
    const float* mw2   = (const float*)d_in[13];
    const float* mb2   = (const float*)d_in[14];
    const float* mw3   = (const float*)d_in[15];
    const float* mb3   = (const float*)d_in[16];

    char* ws = (char*)d_ws;
    __bf16* hbuf = (__bf16*)ws;                                   // 131072*256 bf16 = 64 MB
    __bf16* wb   = (__bf16*)(ws + (size_t)N_NODES * HID * 2);     // bf16 weights, 1.13 MB
    __bf16* w2b  = wb;
    __bf16* w3b  = wb + 65536;
    __bf16* mw1b = wb + 131072;
    __bf16* mw2b = wb + 393216;
    __bf16* mw3b = wb + 524288;

    prep_kernel<<<2304, 256, 0, stream>>>(wb, ip_w2, ip_w3, mw1, mw2, mw3);
    encoder_kernel<<<2048, 256, 0, stream>>>(x, pos, ip_w1, ip_b1, w2b, ip_b2,
                                             w3b, ip_b3, bfour, hbuf);
    message_kernel<<<4096, 256, 0, stream>>>(hbuf, edges, mw1b, mb1, mw2b, mb2,
                                             mw3b, mb3, (float*)d_out);
}

// Round 2
// 906.217 us; speedup vs baseline: 2.7678x; 2.7678x over previous
//
#include <hip/hip_runtime.h>
#include <math.h>

#define N_NODES 131072
#define N_DST   16384
#define DEG     16
#define HID     256
#define N_EDGES 262144

typedef __bf16 bf16_8 __attribute__((ext_vector_type(8)));
typedef float  f32_4  __attribute__((ext_vector_type(4)));

__device__ __forceinline__ float gelu_f(float v) {
    return 0.5f * v * (1.0f + erff(v * 0.70710678f));
}
__device__ __forceinline__ f32_4 zero4() {
    f32_4 z; z[0] = 0.f; z[1] = 0.f; z[2] = 0.f; z[3] = 0.f; return z;
}

// async global->LDS, 16B per lane. LDS side must be wave-uniform base + lane*16.
__device__ __forceinline__ void load_lds16(const __bf16* g, __bf16* l) {
    __builtin_amdgcn_global_load_lds(
        (__attribute__((address_space(1))) void*)g,
        (__attribute__((address_space(3))) void*)l, 16, 0, 0);
}

// ---------------- prep: fp32 -> bf16 weights ----------------
// layout (elements): w2b[65536] w3b[65536] mw1b[262144] mw2b[131072] mw3b[65536]
__global__ void prep_kernel(__bf16* __restrict__ out,
                            const float* __restrict__ w2,
                            const float* __restrict__ w3,
                            const float* __restrict__ mw1,
                            const float* __restrict__ mw2,
                            const float* __restrict__ mw3) {
    int stride = gridDim.x * blockDim.x;
    for (int i = blockIdx.x * blockDim.x + threadIdx.x; i < 589824; i += stride) {
        float v;
        if      (i <  65536) v = w2[i];
        else if (i < 131072) v = w3[i - 65536];
        else if (i < 393216) v = mw1[i - 131072];
        else if (i < 524288) v = mw2[i - 393216];
        else                 v = mw3[i - 524288];
        out[i] = (__bf16)v;
    }
}

// ---------------- encoder: h = MLP(x) + fourier(pos), bf16 out ----------------
__global__ __launch_bounds__(256) void encoder_kernel(
    const float* __restrict__ x, const float* __restrict__ pos,
    const float* __restrict__ w1, const float* __restrict__ b1,
    const __bf16* __restrict__ w2, const float* __restrict__ b2,
    const __bf16* __restrict__ w3, const float* __restrict__ b3,
    const float* __restrict__ bfour,
    __bf16* __restrict__ hout) {
    __shared__ float s_w1[3 * 256];
    __shared__ float s_b1[256];
    __shared__ float s_x[64 * 3];
    __shared__ float s_pos[64 * 2];
    __shared__ __align__(16) __bf16 s_h[64 * 256];  // swizzled: (m,k) -> m*256 + ((k + m*8)&255)

    const int tid = threadIdx.x;
    const int node0 = blockIdx.x * 64;

    s_w1[tid]       = w1[tid * 3 + 0];
    s_w1[256 + tid] = w1[tid * 3 + 1];
    s_w1[512 + tid] = w1[tid * 3 + 2];
    s_b1[tid]       = b1[tid];
    if (tid < 192) s_x[tid] = x[node0 * 3 + tid];
    if (tid < 128) s_pos[tid] = pos[node0 * 2 + tid];
    __syncthreads();

    {
        const float wa = s_w1[tid], wb = s_w1[256 + tid], wc = s_w1[512 + tid], bb = s_b1[tid];
        #pragma unroll 4
        for (int n = 0; n < 64; n++) {
            float v = fmaf(s_x[n * 3 + 2], wc,
                      fmaf(s_x[n * 3 + 1], wb,
                      fmaf(s_x[n * 3 + 0], wa, bb)));
            s_h[n * 256 + ((tid + n * 8) & 255)] = (__bf16)gelu_f(v);
        }
    }
    __syncthreads();

    const int wave = tid >> 6;
    const int lane = tid & 63;
    const int ln   = lane & 15;
    const int quad = lane >> 4;
    const int mA   = wave * 16 + ln;

    f32_4 acc[16];

    #pragma unroll
    for (int i = 0; i < 16; i++) acc[i] = zero4();
    #pragma unroll
    for (int ks = 0; ks < 8; ks++) {
        int k0 = ks * 32 + quad * 8;
        bf16_8 a = *(const bf16_8*)&s_h[mA * 256 + ((k0 + mA * 8) & 255)];
        #pragma unroll
        for (int nt = 0; nt < 16; nt++) {
            bf16_8 b = *(const bf16_8*)(w2 + (nt * 16 + ln) * 256 + k0);
            acc[nt] = __builtin_amdgcn_mfma_f32_16x16x32_bf16(a, b, acc[nt], 0, 0, 0);
        }
    }
    __syncthreads();
    #pragma unroll
    for (int nt = 0; nt < 16; nt++) {
        int col = nt * 16 + ln;
        float bv = b2[col];
        #pragma unroll
        for (int r = 0; r < 4; r++) {
            int row = wave * 16 + quad * 4 + r;
            s_h[row * 256 + ((col + row * 8) & 255)] = (__bf16)gelu_f(acc[nt][r] + bv);
        }
    }
    __syncthreads();

    #pragma unroll
    for (int i = 0; i < 16; i++) acc[i] = zero4();
    #pragma unroll
    for (int ks = 0; ks < 8; ks++) {
        int k0 = ks * 32 + quad * 8;
        bf16_8 a = *(const bf16_8*)&s_h[mA * 256 + ((k0 + mA * 8) & 255)];
        #pragma unroll
        for (int nt = 0; nt < 16; nt++) {
            bf16_8 b = *(const bf16_8*)(w3 + (nt * 16 + ln) * 256 + k0);
            acc[nt] = __builtin_amdgcn_mfma_f32_16x16x32_bf16(a, b, acc[nt], 0, 0, 0);
        }
    }
    #pragma unroll
    for (int nt = 0; nt < 16; nt++) {
        int col = nt * 16 + ln;
        float bv = b3[col];
        int jm = col & 127;
        float B0 = bfour[jm * 2 + 0] * 6.2831853071795864f;
        float B1 = bfour[jm * 2 + 1] * 6.2831853071795864f;
        #pragma unroll
        for (int r = 0; r < 4; r++) {
            int row = wave * 16 + quad * 4 + r;
            float f = s_pos[row * 2 + 0] * B0 + s_pos[row * 2 + 1] * B1;
            float ff = (col < 128) ? cosf(f) : sinf(f);
            hout[(node0 + row) * 256 + col] = (__bf16)(acc[nt][r] + bv + ff);
        }
    }
}

// ---------------- message-path GEMM: C = act(A @ W^T + b), optional gather / pool ----
// 256 threads = 4 waves (2x2), block tile 128(M)x128(N), wave tile 64x64, BK=64.
// LDS staged via global_load_lds w/ XOR swizzle: slot(row,kgs) holds kg = kgs^(row&7).
template<int K, bool GATHER, bool GELU, bool POOL>
__global__ __launch_bounds__(256, 3) void mgemm(
    const __bf16* __restrict__ Ag, const __bf16* __restrict__ h,
    const int* __restrict__ edges, const __bf16* __restrict__ W,
    const float* __restrict__ bias, __bf16* __restrict__ Cb,
    float* __restrict__ Cf, int NB, int Nfull, int e0)
{
    __shared__ __align__(16) __bf16 sA[128 * 64];
    __shared__ __align__(16) __bf16 sB[128 * 64];
    __shared__ int s_src[128];
    __shared__ int s_dst[128];

    const int tid  = threadIdx.x;
    const int mblk = blockIdx.x / NB;
    const int nblk = blockIdx.x % NB;
    const int m0 = mblk * 128, n0 = nblk * 128;
    const int wave = tid >> 6, lane = tid & 63, ln = lane & 15, quad = lane >> 4;
    const int wm = wave >> 1, wn = wave & 1;

    if (GATHER && tid < 128) {
        int e = e0 + m0 + tid;
        s_src[tid] = edges[2 * e + 1];
        s_dst[tid] = edges[2 * e + 0];
    }

    f32_4 acc[4][4];
    #pragma unroll
    for (int i = 0; i < 4; i++)
        #pragma unroll
        for (int j = 0; j < 4; j++) acc[i][j] = zero4();

    for (int kb = 0; kb < K / 64; kb++) {
        __syncthreads();  // previous tile consumed (and s_src visible at kb=0)
        #pragma unroll
        for (int i = 0; i < 4; i++) {
            int idx = i * 256 + tid;
            int row = idx >> 3, kgs = idx & 7;
            int kg  = kgs ^ (row & 7);
            const __bf16* gsrc;
            if (GATHER) {
                int col  = kb * 64 + kg * 8;
                int node = (col < 256) ? s_src[row] : s_dst[row];
                gsrc = h + (size_t)node * HID + (col & 255);
            } else {
                gsrc = Ag + (size_t)(m0 + row) * K + kb * 64 + kg * 8;
            }
            load_lds16(gsrc, &sA[idx * 8]);
            const __bf16* gw = W + (size_t)(n0 + row) * K + kb * 64 + kg * 8;
            load_lds16(gw, &sB[idx * 8]);
        }
        __syncthreads();  // drains vmcnt (DMA) per compiler barrier semantics
        #pragma unroll
        for (int ks = 0; ks < 2; ks++) {
            bf16_8 af[4], bfr[4];
            int kg = ks * 4 + quad;
            #pragma unroll
            for (int mt = 0; mt < 4; mt++) {
                int mr = wm * 64 + mt * 16 + ln;
                af[mt] = *(const bf16_8*)&sA[mr * 64 + (kg ^ (mr & 7)) * 8];
            }
            #pragma unroll
            for (int nt = 0; nt < 4; nt++) {
                int nr = wn * 64 + nt * 16 + ln;
                bfr[nt] = *(const bf16_8*)&sB[nr * 64 + (kg ^ (nr & 7)) * 8];
            }
            #pragma unroll
            for (int mt = 0; mt < 4; mt++)
                #pragma unroll
                for (int nt = 0; nt < 4; nt++)
                    acc[mt][nt] = __builtin_amdgcn_mfma_f32_16x16x32_bf16(af[mt], bfr[nt], acc[mt][nt], 0, 0, 0);
        }
    }

    if (!POOL) {
        #pragma unroll
        for (int nt = 0; nt < 4; nt++) {
            int col = n0 + wn * 64 + nt * 16 + ln;
            float bb = bias[col];
            #pragma unroll
            for (int mt = 0; mt < 4; mt++) {
                #pragma unroll
                for (int r = 0; r < 4; r++) {
                    int rowE = m0 + wm * 64 + mt * 16 + quad * 4 + r;
                    float v = acc[mt][nt][r] + bb;
                    if (GELU) v = gelu_f(v);
                    Cb[(size_t)rowE * Nfull + col] = (__bf16)v;
                }
            }
        }
    } else {
        // each 16-row m-tile is exactly one dst group (DEG=16): in-register mean
        #pragma unroll
        for (int nt = 0; nt < 4; nt++) {
            int col = n0 + wn * 64 + nt * 16 + ln;
            float bb = bias[col];
            #pragma unroll
            for (int mt = 0; mt < 4; mt++) {
                float s = acc[mt][nt][0] + acc[mt][nt][1] + acc[mt][nt][2] + acc[mt][nt][3];
                s += __shfl_xor(s, 16);
                s += __shfl_xor(s, 32);
                if (quad == 0) {
                    int eg  = e0 + m0 + wm * 64 + mt * 16;
                    int dst = edges[2 * eg];
                    Cf[(size_t)dst * HID + col] = s * 0.0625f + bb;
                }
            }
        }
    }
}

extern "C" void kernel_launch(void* const* d_in, const int* in_sizes, int n_in,
                              void* d_out, int out_size, void* d_ws, size_t ws_size,
                              hipStream_t stream) {
    const float* x     = (const float*)d_in[0];
    const float* pos   = (const float*)d_in[1];
    const int*   edges = (const int*)d_in[2];
    const float* ip_w1 = (const float*)d_in[4];
    const float* ip_b1 = (const float*)d_in[5];
    const float* ip_w2 = (const float*)d_in[6];
    const float* ip_b2 = (const float*)d_in[7];
    const float* ip_w3 = (const float*)d_in[8];
    const float* ip_b3 = (const float*)d_in[9];
    const float* bfour = (const float*)d_in[10];
    const float* mw1   = (const float*)d_in[11];
    const float* mb1   = (const float*)d_in[12];
    const float* mw2   = (const float*)d_in[13];
    const float* mb2   = (const float*)d_in[14];
    const float* mw3   = (const float*)d_in[15];
    const float* mb3   = (const float*)d_in[16];

    char* ws = (char*)d_ws;
    __bf16* hbuf = (__bf16*)ws;                              // 64 MB
    size_t off = (size_t)N_NODES * HID * 2;
    __bf16* wb = (__bf16*)(ws + off);                        // 1.125 MB bf16 weights
    off += (size_t)589824 * 2;
    off = (off + 255) & ~(size_t)255;
    char* scratch = ws + off;
    size_t avail = ws_size > off ? ws_size - off : 0;

    // chunk edges so m1 (eC*512) + m2 (eC*256) bf16 fit in remaining workspace
    int C = 1;
    while (C < 16 && ((size_t)N_EDGES / C) * (512 + 256) * 2 > avail) C <<= 1;
    const int eC  = N_EDGES / C;   // edges per chunk (multiple of 2048)
    const int mbC = eC / 128;      // M-blocks per chunk

    __bf16* w2b  = wb;
    __bf16* w3b  = wb + 65536;
    __bf16* mw1b = wb + 131072;
    __bf16* mw2b = wb + 393216;
    __bf16* mw3b = wb + 524288;
    __bf16* m1c  = (__bf16*)scratch;
    __bf16* m2c  = m1c + (size_t)eC * 512;

    prep_kernel<<<2304, 256, 0, stream>>>(wb, ip_w2, ip_w3, mw1, mw2, mw3);
    encoder_kernel<<<2048, 256, 0, stream>>>(x, pos, ip_w1, ip_b1, w2b, ip_b2,
                                             w3b, ip_b3, bfour, hbuf);

    for (int c = 0; c < C; c++) {
        int e0 = c * eC;
        mgemm<512, true,  true,  false><<<mbC * 4, 256, 0, stream>>>(
            nullptr, hbuf, edges, mw1b, mb1, m1c, nullptr, 4, 512, e0);
        mgemm<512, false, true,  false><<<mbC * 2, 256, 0, stream>>>(
            m1c, nullptr, edges, mw2b, mb2, m2c, nullptr, 2, 256, e0);
        mgemm<256, false, false, true ><<<mbC * 2, 256, 0, stream>>>(
            m2c, nullptr, edges, mw3b, mb3, nullptr, (float*)d_out, 2, 256, e0);
    }
}

// Round 3
// 690.614 us; speedup vs baseline: 3.6319x; 1.3122x over previous
//
#include <hip/hip_runtime.h>
#include <math.h>

#define N_NODES 131072
#define N_DST   16384
#define DEG     16
#define HID     256
#define N_EDGES 262144

typedef __bf16 bf16_8 __attribute__((ext_vector_type(8)));
typedef float  f32_4  __attribute__((ext_vector_type(4)));

__device__ __forceinline__ float gelu_f(float v) {
    return 0.5f * v * (1.0f + erff(v * 0.70710678f));
}
__device__ __forceinline__ f32_4 zero4() {
    f32_4 z; z[0] = 0.f; z[1] = 0.f; z[2] = 0.f; z[3] = 0.f; return z;
}

// async global->LDS, 16B per lane. LDS side must be wave-uniform base + lane*16.
__device__ __forceinline__ void load_lds16(const __bf16* g, __bf16* l) {
    __builtin_amdgcn_global_load_lds(
        (__attribute__((address_space(1))) void*)g,
        (__attribute__((address_space(3))) void*)l, 16, 0, 0);
}

// ---------------- prep: fp32 -> bf16 weights ----------------
// layout (elements): w2b[65536] w3b[65536] mw1b[262144] mw2b[131072] mw3b[65536]
__global__ void prep_kernel(__bf16* __restrict__ out,
                            const float* __restrict__ w2,
                            const float* __restrict__ w3,
                            const float* __restrict__ mw1,
                            const float* __restrict__ mw2,
                            const float* __restrict__ mw3) {
    int stride = gridDim.x * blockDim.x;
    for (int i = blockIdx.x * blockDim.x + threadIdx.x; i < 589824; i += stride) {
        float v;
        if      (i <  65536) v = w2[i];
        else if (i < 131072) v = w3[i - 65536];
        else if (i < 393216) v = mw1[i - 131072];
        else if (i < 524288) v = mw2[i - 393216];
        else                 v = mw3[i - 524288];
        out[i] = (__bf16)v;
    }
}

// ---------------- encoder layer 1 (K=3): h1 = gelu(x @ W1^T + b1), bf16 ----------------
// thread = (node, 8-col group); coalesced bf16x8 stores (512 B/segment per half-wave)
__global__ __launch_bounds__(256) void enc1_kernel(
    const float* __restrict__ x, const float* __restrict__ w1,
    const float* __restrict__ b1, __bf16* __restrict__ h1) {
    int gid = blockIdx.x * 256 + threadIdx.x;
    int n = gid >> 5, c8 = gid & 31;
    float x0 = x[n * 3 + 0], x1 = x[n * 3 + 1], x2 = x[n * 3 + 2];
    bf16_8 o;
    #pragma unroll
    for (int j = 0; j < 8; j++) {
        int cc = c8 * 8 + j;
        float v = fmaf(x2, w1[cc * 3 + 2],
                  fmaf(x1, w1[cc * 3 + 1],
                  fmaf(x0, w1[cc * 3 + 0], b1[cc])));
        o[j] = (__bf16)gelu_f(v);
    }
    *(bf16_8*)&h1[(size_t)n * 256 + c8 * 8] = o;
}

// ---------------- tiled GEMM: C = act(A @ W^T + b) [+fourier] [+pool], optional gather ----
// 256 threads = 4 waves (2x2), block tile 128(M)x128(N), wave tile 64x64, BK=64.
// LDS staged via global_load_lds w/ XOR swizzle: slot(row,kgs) holds kg = kgs^(row&7).
template<int K, bool GATHER, bool GELU, bool POOL, bool FOURIER>
__global__ __launch_bounds__(256, 3) void mgemm(
    const __bf16* __restrict__ Ag, const __bf16* __restrict__ h,
    const int* __restrict__ edges, const __bf16* __restrict__ W,
    const float* __restrict__ bias, __bf16* __restrict__ Cb,
    float* __restrict__ Cf, const float* __restrict__ pos,
    const float* __restrict__ bfour, int NB, int Nfull, int e0)
{
    __shared__ __align__(16) __bf16 sA[128 * 64];
    __shared__ __align__(16) __bf16 sB[128 * 64];
    __shared__ int s_src[128];
    __shared__ int s_dst[128];

    const int tid  = threadIdx.x;
    const int mblk = blockIdx.x / NB;
    const int nblk = blockIdx.x % NB;
    const int m0 = mblk * 128, n0 = nblk * 128;
    const int wave = tid >> 6, lane = tid & 63, ln = lane & 15, quad = lane >> 4;
    const int wm = wave >> 1, wn = wave & 1;

    if (GATHER && tid < 128) {
        int e = e0 + m0 + tid;
        s_src[tid] = edges[2 * e + 1];
        s_dst[tid] = edges[2 * e + 0];
    }

    f32_4 acc[4][4];
    #pragma unroll
    for (int i = 0; i < 4; i++)
        #pragma unroll
        for (int j = 0; j < 4; j++) acc[i][j] = zero4();

    for (int kb = 0; kb < K / 64; kb++) {
        __syncthreads();  // previous tile consumed (and s_src visible at kb=0)
        #pragma unroll
        for (int i = 0; i < 4; i++) {
            int idx = i * 256 + tid;
            int row = idx >> 3, kgs = idx & 7;
            int kg  = kgs ^ (row & 7);
            const __bf16* gsrc;
            if (GATHER) {
                int col  = kb * 64 + kg * 8;
                int node = (col < 256) ? s_src[row] : s_dst[row];
                gsrc = h + (size_t)node * HID + (col & 255);
            } else {
                gsrc = Ag + (size_t)(m0 + row) * K + kb * 64 + kg * 8;
            }
            load_lds16(gsrc, &sA[idx * 8]);
            const __bf16* gw = W + (size_t)(n0 + row) * K + kb * 64 + kg * 8;
            load_lds16(gw, &sB[idx * 8]);
        }
        __syncthreads();  // drains vmcnt (DMA) per compiler barrier semantics
        #pragma unroll
        for (int ks = 0; ks < 2; ks++) {
            bf16_8 af[4], bfr[4];
            int kg = ks * 4 + quad;
            #pragma unroll
            for (int mt = 0; mt < 4; mt++) {
                int mr = wm * 64 + mt * 16 + ln;
                af[mt] = *(const bf16_8*)&sA[mr * 64 + (kg ^ (mr & 7)) * 8];
            }
            #pragma unroll
            for (int nt = 0; nt < 4; nt++) {
                int nr = wn * 64 + nt * 16 + ln;
                bfr[nt] = *(const bf16_8*)&sB[nr * 64 + (kg ^ (nr & 7)) * 8];
            }
            #pragma unroll
            for (int mt = 0; mt < 4; mt++)
                #pragma unroll
                for (int nt = 0; nt < 4; nt++)
                    acc[mt][nt] = __builtin_amdgcn_mfma_f32_16x16x32_bf16(af[mt], bfr[nt], acc[mt][nt], 0, 0, 0);
        }
    }

    if (POOL) {
        // each 16-row m-tile is exactly one dst group (DEG=16): in-register mean
        #pragma unroll
        for (int nt = 0; nt < 4; nt++) {
            int col = n0 + wn * 64 + nt * 16 + ln;
            float bb = bias[col];
            #pragma unroll
            for (int mt = 0; mt < 4; mt++) {
                float s = acc[mt][nt][0] + acc[mt][nt][1] + acc[mt][nt][2] + acc[mt][nt][3];
                s += __shfl_xor(s, 16);
                s += __shfl_xor(s, 32);
                if (quad == 0) {
                    int eg  = e0 + m0 + wm * 64 + mt * 16;
                    int dst = edges[2 * eg];
                    Cf[(size_t)dst * HID + col] = s * 0.0625f + bb;
                }
            }
        }
    } else {
        // epilogue: bias [+gelu] [+fourier], then LDS-transpose for coalesced 16B stores
        __syncthreads();  // K-loop LDS reads done; reuse sA/sB as staging
        __bf16* sw = ((wave & 2) ? sB : sA) + (wave & 1) * 4096;  // 64x64 bf16 per wave
        float bbv[4], Bc0[4], Bc1[4];
        #pragma unroll
        for (int nt = 0; nt < 4; nt++) {
            int col = n0 + wn * 64 + nt * 16 + ln;
            bbv[nt] = bias[col];
            if (FOURIER) {
                int jm = col & 127;
                Bc0[nt] = bfour[jm * 2 + 0];
                Bc1[nt] = bfour[jm * 2 + 1];
            }
        }
        const bool iscos = FOURIER && ((n0 + wn * 64) < 128);  // wave-uniform (64 | 128)
        #pragma unroll
        for (int mt = 0; mt < 4; mt++) {
            #pragma unroll
            for (int r = 0; r < 4; r++) {
                int rowL = mt * 16 + quad * 4 + r;
                float p0 = 0.f, p1 = 0.f;
                if (FOURIER) {
                    int rowE = m0 + wm * 64 + rowL;
                    p0 = pos[rowE * 2 + 0];
                    p1 = pos[rowE * 2 + 1];
                }
                #pragma unroll
                for (int nt = 0; nt < 4; nt++) {
                    float v = acc[mt][nt][r] + bbv[nt];
                    if (GELU) v = gelu_f(v);
                    if (FOURIER) {
                        float f = 6.2831853071795864f * fmaf(p1, Bc1[nt], p0 * Bc0[nt]);
                        v += iscos ? __cosf(f) : __sinf(f);
                    }
                    int colL = nt * 16 + ln;
                    sw[rowL * 64 + ((colL + rowL * 8) & 63)] = (__bf16)v;
                }
            }
        }
        __syncthreads();  // guarantee LDS writes drained before transpose reads
        #pragma unroll
        for (int p = 0; p < 8; p++) {
            int rowL = p * 8 + (lane >> 3);
            int c8 = lane & 7;
            bf16_8 vv = *(const bf16_8*)&sw[rowL * 64 + ((c8 * 8 + rowL * 8) & 63)];
            int rowE = m0 + wm * 64 + rowL;
            *(bf16_8*)&Cb[(size_t)rowE * Nfull + n0 + wn * 64 + c8 * 8] = vv;
        }
    }
}

extern "C" void kernel_launch(void* const* d_in, const int* in_sizes, int n_in,
                              void* d_out, int out_size, void* d_ws, size_t ws_size,
                              hipStream_t stream) {
    const float* x     = (const float*)d_in[0];
    const float* pos   = (const float*)d_in[1];
    const int*   edges = (const int*)d_in[2];
    const float* ip_w1 = (const float*)d_in[4];
    const float* ip_b1 = (const float*)d_in[5];
    const float* ip_w2 = (const float*)d_in[6];
    const float* ip_b2 = (const float*)d_in[7];
    const float* ip_w3 = (const float*)d_in[8];
    const float* ip_b3 = (const float*)d_in[9];
    const float* bfour = (const float*)d_in[10];
    const float* mw1   = (const float*)d_in[11];
    const float* mb1   = (const float*)d_in[12];
    const float* mw2   = (const float*)d_in[13];
    const float* mb2   = (const float*)d_in[14];
    const float* mw3   = (const float*)d_in[15];
    const float* mb3   = (const float*)d_in[16];

    char* ws = (char*)d_ws;
    __bf16* hA = (__bf16*)ws;                                // 64 MB: h1, later final h
    __bf16* hB = hA + (size_t)N_NODES * HID;                 // 64 MB: h2 temp
    size_t off = (size_t)N_NODES * HID * 2 * 2;
    __bf16* wb = (__bf16*)(ws + off);                        // 1.125 MB bf16 weights
    off += (size_t)589824 * 2;
    off = (off + 255) & ~(size_t)255;
    char* scratch = ws + off;
    size_t avail = ws_size > off ? ws_size - off : 0;

    // chunk edges so m1 (eC*512) + m2 (eC*256) bf16 fit in remaining workspace
    int C = 1;
    while (C < 16 && ((size_t)N_EDGES / C) * (512 + 256) * 2 > avail) C <<= 1;
    const int eC  = N_EDGES / C;   // edges per chunk (multiple of 2048)
    const int mbC = eC / 128;      // M-blocks per chunk

    __bf16* w2b  = wb;
    __bf16* w3b  = wb + 65536;
    __bf16* mw1b = wb + 131072;
    __bf16* mw2b = wb + 393216;
    __bf16* mw3b = wb + 524288;
    __bf16* m1c  = (__bf16*)scratch;
    __bf16* m2c  = m1c + (size_t)eC * 512;

    prep_kernel<<<2304, 256, 0, stream>>>(wb, ip_w2, ip_w3, mw1, mw2, mw3);

    // encoder: h1 -> hA; h2 = gelu(h1 W2^T+b2) -> hB; h = h2 W3^T+b3+fourier -> hA
    enc1_kernel<<<16384, 256, 0, stream>>>(x, ip_w1, ip_b1, hA);
    mgemm<256, false, true,  false, false><<<2048, 256, 0, stream>>>(
        hA, nullptr, nullptr, w2b, ip_b2, hB, nullptr, nullptr, nullptr, 2, 256, 0);
    mgemm<256, false, false, false, true ><<<2048, 256, 0, stream>>>(
        hB, nullptr, nullptr, w3b, ip_b3, hA, nullptr, pos, bfour, 2, 256, 0);

    for (int c = 0; c < C; c++) {
        int e0 = c * eC;
        mgemm<512, true,  true,  false, false><<<mbC * 4, 256, 0, stream>>>(
            nullptr, hA, edges, mw1b, mb1, m1c, nullptr, nullptr, nullptr, 4, 512, e0);
        mgemm<512, false, true,  false, false><<<mbC * 2, 256, 0, stream>>>(
            m1c, nullptr, edges, mw2b, mb2, m2c, nullptr, nullptr, nullptr, 2, 256, e0);
        mgemm<256, false, false, true,  false><<<mbC * 2, 256, 0, stream>>>(
            m2c, nullptr, edges, mw3b, mb3, nullptr, (float*)d_out, nullptr, nullptr, 2, 256, e0);
    }
}